// Round 1
// baseline (543.846 us; speedup 1.0000x reference)
//
#include <hip/hip_runtime.h>

typedef unsigned short u16;
typedef unsigned int u32;
typedef __bf16 bf16x8 __attribute__((ext_vector_type(8)));
typedef float f32x4 __attribute__((ext_vector_type(4)));
typedef u32 u32x2 __attribute__((ext_vector_type(2)));
typedef u32 u32x4 __attribute__((ext_vector_type(4)));

// B=65536, I=64, H=64, T=16, G=3H=192

__device__ __forceinline__ u16 f2bf(float f) {
  union { float f; u32 u; } v; v.f = f;
  u32 u = v.u;
  u32 r = (u + 0x7fffu + ((u >> 16) & 1u)) >> 16;  // round-nearest-even
  return (u16)r;
}
__device__ __forceinline__ float bf2f(u16 h) {
  union { u32 u; float f; } v; v.u = ((u32)h) << 16;
  return v.f;
}
__device__ __forceinline__ u32 pack2(float a, float b) {
  return (u32)f2bf(a) | ((u32)f2bf(b) << 16);
}
__device__ __forceinline__ float sigf(float x) { return 1.0f / (1.0f + __expf(-x)); }
__device__ __forceinline__ float tanh_fast(float x) { return 2.0f * sigf(2.0f * x) - 1.0f; }

// ---------------- K0: convert weights fp32 -> bf16 (layouts unchanged) ----------------
__global__ __launch_bounds__(256) void k0_convert(
    const float* __restrict__ Wih, const float* __restrict__ Whh,
    const float* __restrict__ cWih, const float* __restrict__ cWhh,
    u16* __restrict__ wih_bf, u16* __restrict__ whh_bf,
    u16* __restrict__ cwih_bf, u16* __restrict__ cwhh_bf)
{
  int i = blockIdx.x * 256 + threadIdx.x;
  if (i < 196608) {          // 16*192*64 and 192*1024
    wih_bf[i]  = f2bf(Wih[i]);
    whh_bf[i]  = f2bf(Whh[i]);
    cwih_bf[i] = f2bf(cWih[i]);
  }
  if (i < 12288) cwhh_bf[i] = f2bf(cWhh[i]);  // 192*64
}

// ---------------- K1: per-type GRU on selected rows only ----------------
// grid (64 chunks, 16 types), 256 threads. Writes hnew[b][h] as bf16.
__global__ __launch_bounds__(256) void k1_pertype(
    const float* __restrict__ x, const int* __restrict__ typ,
    const float* __restrict__ regs,
    const u16* __restrict__ wih_bf, const u16* __restrict__ whh_bf,
    const float* __restrict__ bih, const float* __restrict__ bhh,
    u16* __restrict__ hnew)
{
  const int t = blockIdx.y;
  const int base = blockIdx.x * 1024;
  const int tid = threadIdx.x;

  __shared__ int s_count;
  __shared__ int s_list[1024];
  __shared__ __align__(16) u16 sAx[16 * 72];
  __shared__ __align__(16) u16 sAh[16 * 72];

  if (tid == 0) s_count = 0;
  __syncthreads();
  for (int i = tid; i < 1024; i += 256) {
    if (typ[base + i] == t) {
      int p = atomicAdd(&s_count, 1);
      s_list[p] = base + i;
    }
  }
  __syncthreads();
  const int count = s_count;
  if (count == 0) return;

  const int lane = tid & 63;
  const int w = tid >> 6;
  const int col = lane & 15;   // = MFMA m / n / D-col index
  const int quad = lane >> 4;
  const int hidx = w * 16 + col;

  // B-operand fragments held in registers for the whole block:
  // b_frag[j] = W[t][n][k], n = gate*64 + hidx, k = s*32 + quad*8 + j
  bf16x8 bw[3][2], bh[3][2];
#pragma unroll
  for (int g = 0; g < 3; ++g) {
    const u16* pw = wih_bf + (t * 192 + g * 64 + hidx) * 64;
    const u16* ph = whh_bf + (t * 192 + g * 64 + hidx) * 64;
#pragma unroll
    for (int s = 0; s < 2; ++s) {
      bw[g][s] = *(const bf16x8*)(pw + s * 32 + quad * 8);
      bh[g][s] = *(const bf16x8*)(ph + s * 32 + quad * 8);
    }
  }
  float vbih[3], vbhh[3];
#pragma unroll
  for (int g = 0; g < 3; ++g) {
    vbih[g] = bih[t * 192 + g * 64 + hidx];
    vbhh[g] = bhh[t * 192 + g * 64 + hidx];
  }

  const int srow = tid >> 4;        // staging row 0..15
  const int sk4 = (tid & 15) * 4;   // staging k offset
  const f32x4 zero = {0.f, 0.f, 0.f, 0.f};

  for (int tile = 0; tile < count; tile += 16) {
    __syncthreads();  // previous epilogue done with sAh
    {
      int r = tile + srow;
      int b = s_list[r < count ? r : count - 1];
      float4 vx = *(const float4*)(x + b * 64 + sk4);
      float4 vh = *(const float4*)(regs + (b * 16 + t) * 64 + sk4);
      u32x2 px, ph2;
      px[0] = pack2(vx.x, vx.y); px[1] = pack2(vx.z, vx.w);
      ph2[0] = pack2(vh.x, vh.y); ph2[1] = pack2(vh.z, vh.w);
      *(u32x2*)(&sAx[srow * 72 + sk4]) = px;
      *(u32x2*)(&sAh[srow * 72 + sk4]) = ph2;
    }
    __syncthreads();

    f32x4 agi[3], agh[3];
#pragma unroll
    for (int g = 0; g < 3; ++g) { agi[g] = zero; agh[g] = zero; }
#pragma unroll
    for (int s = 0; s < 2; ++s) {
      bf16x8 ax = *(const bf16x8*)(&sAx[col * 72 + s * 32 + quad * 8]);
      bf16x8 ah = *(const bf16x8*)(&sAh[col * 72 + s * 32 + quad * 8]);
#pragma unroll
      for (int g = 0; g < 3; ++g) {
        agi[g] = __builtin_amdgcn_mfma_f32_16x16x32_bf16(ax, bw[g][s], agi[g], 0, 0, 0);
        agh[g] = __builtin_amdgcn_mfma_f32_16x16x32_bf16(ah, bh[g][s], agh[g], 0, 0, 0);
      }
    }
    // D layout: col = lane&15, row = quad*4 + rr
#pragma unroll
    for (int rr = 0; rr < 4; ++rr) {
      int m = quad * 4 + rr;
      int gr = tile + m;
      if (gr < count) {
        int b2 = s_list[gr];
        float ir  = agi[0][rr] + vbih[0];
        float iz  = agi[1][rr] + vbih[1];
        float in_ = agi[2][rr] + vbih[2];
        float hr  = agh[0][rr] + vbhh[0];
        float hz  = agh[1][rr] + vbhh[1];
        float hn  = agh[2][rr] + vbhh[2];
        float rg = sigf(ir + hr);
        float zg = sigf(iz + hz);
        float ng = tanh_fast(in_ + rg * hn);
        float hold = bf2f(sAh[m * 72 + hidx]);
        hnew[b2 * 64 + hidx] = f2bf((1.f - zg) * ng + zg * hold);
      }
    }
  }
}

// ---------------- K2: core GEMM (B x 1024 @ 1024 x 192) + core GRU, fused ----------------
// grid 1024 blocks (64 rows each), 256 threads (4 waves).
// Wave w owns gate-triple columns {w*16.., 64+w*16.., 128+w*16..} so the GRU
// epilogue needs no cross-wave data.
__global__ __launch_bounds__(256) void k2_core(
    const float* __restrict__ regs, const int* __restrict__ typ,
    const float* __restrict__ c, const u16* __restrict__ hnew,
    const u16* __restrict__ cwih_bf, const u16* __restrict__ cwhh_bf,
    const float* __restrict__ cbih, const float* __restrict__ cbhh,
    float* __restrict__ out)
{
  __shared__ __align__(16) u16 sA[64 * 72];
  __shared__ __align__(16) u16 sB[192 * 72];
  __shared__ int s_typ[64];

  const int tid = threadIdx.x;
  const int rowbase = blockIdx.x * 64;
  if (tid < 64) s_typ[tid] = typ[rowbase + tid];

  const int lane = tid & 63;
  const int w = tid >> 6;
  const int col = lane & 15;
  const int quad = lane >> 4;
  const f32x4 zero = {0.f, 0.f, 0.f, 0.f};

  f32x4 agi[4][3];
#pragma unroll
  for (int mt = 0; mt < 4; ++mt)
#pragma unroll
    for (int g = 0; g < 3; ++g) agi[mt][g] = zero;

  for (int s = 0; s < 16; ++s) {
    __syncthreads();
    // stage B tile: cWih rows n=0..191, k-slot s (64 wide), bf16
#pragma unroll
    for (int j = 0; j < 6; ++j) {
      int u = tid + 256 * j;
      int n = u >> 3, ko = (u & 7) * 8;
      *(u32x4*)(&sB[n * 72 + ko]) = *(const u32x4*)(cwih_bf + n * 1024 + s * 64 + ko);
    }
    // stage A tile with register-slot substitution
#pragma unroll
    for (int j = 0; j < 4; ++j) {
      int v = tid + 256 * j;
      int row = v >> 4, k4 = (v & 15) * 4;
      int b = rowbase + row;
      if (s_typ[row] == s) {
        *(u32x2*)(&sA[row * 72 + k4]) = *(const u32x2*)(hnew + b * 64 + k4);
      } else {
        float4 vv = *(const float4*)(regs + (b * 16 + s) * 64 + k4);
        u32x2 pp; pp[0] = pack2(vv.x, vv.y); pp[1] = pack2(vv.z, vv.w);
        *(u32x2*)(&sA[row * 72 + k4]) = pp;
      }
    }
    __syncthreads();
#pragma unroll
    for (int ks = 0; ks < 2; ++ks) {
      bf16x8 bfr[3];
#pragma unroll
      for (int g = 0; g < 3; ++g)
        bfr[g] = *(const bf16x8*)(&sB[(g * 64 + w * 16 + col) * 72 + ks * 32 + quad * 8]);
#pragma unroll
      for (int mt = 0; mt < 4; ++mt) {
        bf16x8 af = *(const bf16x8*)(&sA[(mt * 16 + col) * 72 + ks * 32 + quad * 8]);
#pragma unroll
        for (int g = 0; g < 3; ++g)
          agi[mt][g] = __builtin_amdgcn_mfma_f32_16x16x32_bf16(af, bfr[g], agi[mt][g], 0, 0, 0);
      }
    }
  }

  // cgh = c @ cWhh^T (kept separate: r-gate multiplies hn)
  f32x4 agh[4][3];
#pragma unroll
  for (int mt = 0; mt < 4; ++mt)
#pragma unroll
    for (int g = 0; g < 3; ++g) agh[mt][g] = zero;

  __syncthreads();
#pragma unroll
  for (int j = 0; j < 6; ++j) {
    int u = tid + 256 * j;
    int n = u >> 3, ko = (u & 7) * 8;
    *(u32x4*)(&sB[n * 72 + ko]) = *(const u32x4*)(cwhh_bf + n * 64 + ko);
  }
#pragma unroll
  for (int j = 0; j < 4; ++j) {
    int v = tid + 256 * j;
    int row = v >> 4, k4 = (v & 15) * 4;
    int b = rowbase + row;
    float4 vv = *(const float4*)(c + b * 64 + k4);
    u32x2 pp; pp[0] = pack2(vv.x, vv.y); pp[1] = pack2(vv.z, vv.w);
    *(u32x2*)(&sA[row * 72 + k4]) = pp;
  }
  __syncthreads();
#pragma unroll
  for (int ks = 0; ks < 2; ++ks) {
    bf16x8 bfr[3];
#pragma unroll
    for (int g = 0; g < 3; ++g)
      bfr[g] = *(const bf16x8*)(&sB[(g * 64 + w * 16 + col) * 72 + ks * 32 + quad * 8]);
#pragma unroll
    for (int mt = 0; mt < 4; ++mt) {
      bf16x8 af = *(const bf16x8*)(&sA[(mt * 16 + col) * 72 + ks * 32 + quad * 8]);
#pragma unroll
      for (int g = 0; g < 3; ++g)
        agh[mt][g] = __builtin_amdgcn_mfma_f32_16x16x32_bf16(af, bfr[g], agh[mt][g], 0, 0, 0);
    }
  }

  // fused core-GRU epilogue
  const int hidx = w * 16 + col;
  float b0 = cbih[hidx], b1 = cbih[64 + hidx], b2 = cbih[128 + hidx];
  float d0 = cbhh[hidx], d1 = cbhh[64 + hidx], d2 = cbhh[128 + hidx];
#pragma unroll
  for (int mt = 0; mt < 4; ++mt) {
#pragma unroll
    for (int rr = 0; rr < 4; ++rr) {
      int row = mt * 16 + quad * 4 + rr;
      int b = rowbase + row;
      float ir  = agi[mt][0][rr] + b0;
      float iz  = agi[mt][1][rr] + b1;
      float in_ = agi[mt][2][rr] + b2;
      float hr  = agh[mt][0][rr] + d0;
      float hz  = agh[mt][1][rr] + d1;
      float hn  = agh[mt][2][rr] + d2;
      float rg = sigf(ir + hr);
      float zg = sigf(iz + hz);
      float ng = tanh_fast(in_ + rg * hn);
      float cold = c[b * 64 + hidx];
      out[b * 64 + hidx] = (1.f - zg) * ng + zg * cold;
    }
  }
}

extern "C" void kernel_launch(void* const* d_in, const int* in_sizes, int n_in,
                              void* d_out, int out_size, void* d_ws, size_t ws_size,
                              hipStream_t stream) {
  const float* x    = (const float*)d_in[0];
  const int*   typ  = (const int*)d_in[1];
  const float* c    = (const float*)d_in[2];
  const float* regs = (const float*)d_in[3];
  const float* Wih  = (const float*)d_in[4];
  const float* Whh  = (const float*)d_in[5];
  const float* bih  = (const float*)d_in[6];
  const float* bhh  = (const float*)d_in[7];
  const float* cWih = (const float*)d_in[8];
  const float* cWhh = (const float*)d_in[9];
  const float* cbih = (const float*)d_in[10];
  const float* cbhh = (const float*)d_in[11];
  float* out = (float*)d_out;

  char* ws = (char*)d_ws;
  u16* hnew    = (u16*)ws;                               // 65536*64*2 = 8 MB
  u16* wih_bf  = (u16*)(ws + (size_t)8 * 1024 * 1024);   // 393216 B
  u16* whh_bf  = wih_bf + 196608;
  u16* cwih_bf = whh_bf + 196608;
  u16* cwhh_bf = cwih_bf + 196608;

  k0_convert<<<768, 256, 0, stream>>>(Wih, Whh, cWih, cWhh, wih_bf, whh_bf, cwih_bf, cwhh_bf);
  k1_pertype<<<dim3(64, 16), 256, 0, stream>>>(x, typ, regs, wih_bf, whh_bf, bih, bhh, hnew);
  k2_core<<<1024, 256, 0, stream>>>(regs, typ, c, hnew, cwih_bf, cwhh_bf, cbih, cbhh, out);
}